// Round 9
// baseline (406.702 us; speedup 1.0000x reference)
//
#include <hip/hip_runtime.h>
#include <hip/hip_fp16.h>
#include <math.h>

#define N_NODES  100000
#define N_EDGES  3200000
#define N_GRAPHS 512
#define DCH      24
#define NLAYERS  4

// 512 nodes per bin -> 196 bins; bucket entry = (node&511)<<17 | src(17b)
#define BINSHIFT 9
#define BINSZ    512
#define NBINS    196      // ceil(100000 / 512)
#define NBINS_P  200
#define CAP      17408    // mean 16384, sigma 128; +8 sigma
#define EPB      8000     // edges per partition block
#define NB_PART  400

// kv row: 64 halves (128 B, 1 cache line). k at [0:24), v at [24:48), rest pad.
#define KVROW    64

// ---------------- kv kernel: k,v = h @ Wk/Wv + b (fp16 packed) ----------------
__global__ __launch_bounds__(256) void kv_kernel(
    const float* __restrict__ h,
    const float* __restrict__ Wk, const float* __restrict__ bk,
    const float* __restrict__ Wv, const float* __restrict__ bv,
    __half* __restrict__ kv)
{
    __shared__ float sW[2 * 576];
    __shared__ float sb[2 * 24];
    for (int i = threadIdx.x; i < 576; i += 256) {
        sW[i] = Wk[i];
        sW[576 + i] = Wv[i];
    }
    if (threadIdx.x < 24) {
        sb[threadIdx.x] = bk[threadIdx.x];
        sb[24 + threadIdx.x] = bv[threadIdx.x];
    }
    __syncthreads();

    int node = blockIdx.x * 256 + threadIdx.x;
    if (node >= N_NODES) return;

    float hx[24];
    const float4* hp = (const float4*)(h + (size_t)node * DCH);
    #pragma unroll
    for (int t = 0; t < 6; t++) {
        float4 f = hp[t];
        hx[4*t] = f.x; hx[4*t+1] = f.y; hx[4*t+2] = f.z; hx[4*t+3] = f.w;
    }

    #pragma unroll
    for (int mtx = 0; mtx < 2; mtx++) {
        float o[24];
        #pragma unroll
        for (int c = 0; c < 24; c++) o[c] = sb[mtx * 24 + c];
        #pragma unroll
        for (int ci = 0; ci < 24; ci++) {
            float hv = hx[ci];
            #pragma unroll
            for (int c = 0; c < 24; c++)
                o[c] += hv * sW[mtx * 576 + ci * 24 + c];
        }
        __half tmp[24];
        #pragma unroll
        for (int c = 0; c < 24; c++) tmp[c] = __float2half_rn(o[c]);
        float4* op = (float4*)(kv + (size_t)node * KVROW + mtx * 24);
        const float4* tp = (const float4*)tmp;
        #pragma unroll
        for (int t = 0; t < 3; t++) op[t] = tp[t];
    }
}

// ---------------- CSR build: slack-bin bucket sort, 512-node bins ----------------
__global__ void cursor_init_kernel(int* __restrict__ cursor)
{
    int t = blockIdx.x * 256 + threadIdx.x;
    if (t < NBINS) cursor[t] = t * CAP;
}

__global__ __launch_bounds__(512) void partition_kernel(
    const int* __restrict__ esrc, const int* __restrict__ edst,
    int* __restrict__ cursor, unsigned int* __restrict__ bucket)
{
    __shared__ int hist[NBINS_P];
    __shared__ int base[NBINS_P];
    for (int t = threadIdx.x; t < NBINS_P; t += 512) hist[t] = 0;
    __syncthreads();
    int e0 = blockIdx.x * EPB;
    int e1 = min(e0 + EPB, N_EDGES);
    for (int e = e0 + threadIdx.x; e < e1; e += 512)
        atomicAdd(&hist[edst[e] >> BINSHIFT], 1);
    __syncthreads();
    for (int t = threadIdx.x; t < NBINS; t += 512) {
        int hcount = hist[t];
        base[t] = hcount ? atomicAdd(&cursor[t], hcount) : 0;
    }
    __syncthreads();
    for (int t = threadIdx.x; t < NBINS_P; t += 512) hist[t] = 0;
    __syncthreads();
    for (int e = e0 + threadIdx.x; e < e1; e += 512) {
        int d = edst[e];
        int b = d >> BINSHIFT;
        int lc = atomicAdd(&hist[b], 1);
        int pos = base[b] + lc;
        if (pos < (b + 1) * CAP)  // overflow guard (never fires for uniform input)
            bucket[pos] = ((unsigned)(d & (BINSZ - 1)) << 17) | (unsigned)esrc[e];
    }
}

__global__ __launch_bounds__(256) void bin_scan_kernel(
    const int* __restrict__ cursor,
    int* __restrict__ bin_base, int* __restrict__ row_start)
{
    __shared__ int sd[256];
    int t = threadIdx.x;
    int v = 0;
    if (t < NBINS) v = min(cursor[t] - t * CAP, CAP);
    sd[t] = v;
    __syncthreads();
    for (int off = 1; off < 256; off <<= 1) {
        int u = (t >= off) ? sd[t - off] : 0;
        __syncthreads();
        sd[t] += u;
        __syncthreads();
    }
    if (t < NBINS) bin_base[t] = sd[t] - v;  // exclusive prefix
    if (t == 0) { bin_base[NBINS] = N_EDGES; row_start[N_NODES] = N_EDGES; }
}

__global__ __launch_bounds__(512) void bin_scatter_kernel(
    const unsigned int* __restrict__ bucket, const int* __restrict__ cursor,
    const int* __restrict__ bin_base,
    int* __restrict__ row_start, int* __restrict__ csr_src)
{
    int b = blockIdx.x;
    int node0 = b << BINSHIFT;
    int nn = min(BINSZ, N_NODES - node0);
    int ebeg = b * CAP;
    int cnt  = min(cursor[b] - b * CAP, CAP);
    int obase = bin_base[b];
    __shared__ int c0[BINSZ], s[BINSZ], cur[BINSZ];
    int tid = threadIdx.x;
    c0[tid] = 0;
    __syncthreads();
    for (int i = tid; i < cnt; i += 512)
        atomicAdd(&c0[bucket[ebeg + i] >> 17], 1);
    __syncthreads();
    s[tid] = c0[tid];
    __syncthreads();
    for (int off = 1; off < 512; off <<= 1) {
        int u = (tid >= off) ? s[tid - off] : 0;
        __syncthreads();
        s[tid] += u;
        __syncthreads();
    }
    if (tid < nn) {
        int ex = obase + s[tid] - c0[tid];
        row_start[node0 + tid] = ex;
        cur[tid] = ex;
    }
    __syncthreads();
    for (int i = tid; i < cnt; i += 512) {
        unsigned p = bucket[ebeg + i];
        int j = p >> 17;
        int pos = atomicAdd(&cur[j], 1);
        csr_src[pos] = (int)(p & 0x1FFFF);
    }
}

// ---------------- fused attention: q/skip computed in-kernel; optional pool fusion ----
// 8 lanes per dst node, 32 nodes per 256-thread block; N_NODES/32 = 3125 exact blocks.
template<int DO_POOL>
__global__ __launch_bounds__(256) void attn_kernel(
    const float* __restrict__ h, const __half* __restrict__ kv,
    const float* __restrict__ Wq, const float* __restrict__ bq,
    const float* __restrict__ Ws, const float* __restrict__ bs,
    const int* __restrict__ row_start, const int* __restrict__ csr_src,
    const int* __restrict__ batch,
    float* __restrict__ out, float* __restrict__ poolc)
{
    __shared__ float sWq[576], sWs[576];
    __shared__ float sbq[24], sbs[24];
    __shared__ float sh[32 * 24];
    __shared__ float sq[32 * 24];
    __shared__ float spool[8][25];

    int tid = threadIdx.x;
    for (int t = tid; t < 576; t += 256) { sWq[t] = Wq[t]; sWs[t] = Ws[t]; }
    if (tid < 24) { sbq[tid] = bq[tid]; sbs[tid] = bs[tid]; }
    if (DO_POOL) {
        for (int t = tid; t < 8 * 25; t += 256) ((float*)spool)[t] = 0.f;
    }
    int node0 = blockIdx.x * 32;
    for (int t = tid; t < 192; t += 256)
        ((float4*)sh)[t] = ((const float4*)(h + (size_t)node0 * DCH))[t];
    __syncthreads();

    int grp = tid >> 3;
    int sub = tid & 7;
    int i = node0 + grp;

    // q columns 3sub..3sub+2 for this node, then exchange via LDS
    {
        const float* hrow = &sh[grp * 24];
        float qc0 = sbq[3*sub], qc1 = sbq[3*sub+1], qc2 = sbq[3*sub+2];
        #pragma unroll
        for (int ci = 0; ci < 24; ci++) {
            float hv = hrow[ci];
            qc0 += hv * sWq[ci*24 + 3*sub];
            qc1 += hv * sWq[ci*24 + 3*sub + 1];
            qc2 += hv * sWq[ci*24 + 3*sub + 2];
        }
        sq[grp*24 + 3*sub]     = qc0;
        sq[grp*24 + 3*sub + 1] = qc1;
        sq[grp*24 + 3*sub + 2] = qc2;
    }
    __syncthreads();

    float qr[24];
    #pragma unroll
    for (int c = 0; c < 24; c++) qr[c] = sq[grp*24 + c];

    float m = -INFINITY, s = 0.f;
    float acc[24];
    #pragma unroll
    for (int c = 0; c < 24; c++) acc[c] = 0.f;

    int beg = row_start[i];
    int end = row_start[i + 1];
    const float scale = 0.2041241452319315f;  // 1/sqrt(24)

    int src_next = (beg + sub < end) ? csr_src[beg + sub] : 0;
    for (int e = beg + sub; e < end; e += 8) {
        int src = src_next;
        src_next = (e + 8 < end) ? csr_src[e + 8] : 0;

        const float4* kvp = (const float4*)(kv + (size_t)src * KVROW);
        float4 kr[3], vr[3];
        #pragma unroll
        for (int t = 0; t < 3; t++) kr[t] = kvp[t];
        #pragma unroll
        for (int t = 0; t < 3; t++) vr[t] = kvp[3 + t];

        const __half2* kh = (const __half2*)kr;
        float dot = 0.f;
        #pragma unroll
        for (int j = 0; j < 12; j++) {
            float2 f = __half22float2(kh[j]);
            dot += qr[2*j] * f.x + qr[2*j+1] * f.y;
        }
        dot *= scale;

        float mn   = fmaxf(m, dot);
        float wold = __expf(m - mn);   // first iter: exp(-inf)=0
        float w    = __expf(dot - mn);
        s = s * wold + w;
        const __half2* vh = (const __half2*)vr;
        #pragma unroll
        for (int j = 0; j < 12; j++) {
            float2 f = __half22float2(vh[j]);
            acc[2*j]   = acc[2*j]   * wold + w * f.x;
            acc[2*j+1] = acc[2*j+1] * wold + w * f.y;
        }
        m = mn;
    }

    // butterfly merge across the 8-lane group (all lanes end with merged state)
    #pragma unroll
    for (int off = 1; off < 8; off <<= 1) {
        float m2 = __shfl_xor(m, off);
        float s2 = __shfl_xor(s, off);
        float mn = fmaxf(m, m2);
        float w1 = (m  == mn) ? 1.f : __expf(m  - mn);  // avoids (-inf)-(-inf)=NaN
        float w2 = (m2 == mn) ? 1.f : __expf(m2 - mn);
        s = s * w1 + s2 * w2;
        #pragma unroll
        for (int c = 0; c < 24; c++) {
            float a2 = __shfl_xor(acc[c], off);
            acc[c] = acc[c] * w1 + a2 * w2;
        }
        m = mn;
    }

    // skip columns 3sub..3sub+2, output o = relu(skip + acc/s)
    float o0, o1, o2;
    {
        const float* hrow = &sh[grp * 24];
        float k0 = sbs[3*sub], k1 = sbs[3*sub+1], k2 = sbs[3*sub+2];
        #pragma unroll
        for (int ci = 0; ci < 24; ci++) {
            float hv = hrow[ci];
            k0 += hv * sWs[ci*24 + 3*sub];
            k1 += hv * sWs[ci*24 + 3*sub + 1];
            k2 += hv * sWs[ci*24 + 3*sub + 2];
        }
        float inv = 1.f / (s + 1e-16f);
        o0 = fmaxf(k0 + acc[3*sub]     * inv, 0.f);
        o1 = fmaxf(k1 + acc[3*sub + 1] * inv, 0.f);
        o2 = fmaxf(k2 + acc[3*sub + 2] * inv, 0.f);
    }

    if (!DO_POOL) {
        size_t base = (size_t)i * DCH + 3*sub;
        out[base] = o0; out[base + 1] = o1; out[base + 2] = o2;
    } else {
        int g  = batch[i];
        int g0 = batch[node0];
        int rel = g - g0;
        if (rel < 8) {
            atomicAdd(&spool[rel][3*sub],     o0);
            atomicAdd(&spool[rel][3*sub + 1], o1);
            atomicAdd(&spool[rel][3*sub + 2], o2);
            if (sub == 0) atomicAdd(&spool[rel][24], 1.f);
        } else {
            atomicAdd(&poolc[g * 25 + 3*sub],     o0);
            atomicAdd(&poolc[g * 25 + 3*sub + 1], o1);
            atomicAdd(&poolc[g * 25 + 3*sub + 2], o2);
            if (sub == 0) atomicAdd(&poolc[g * 25 + 24], 1.f);
        }
        __syncthreads();
        for (int t = tid; t < 8 * 25; t += 256) {
            int slot = t / 25, c = t % 25;
            float val = spool[slot][c];
            if (val != 0.f)
                atomicAdd(&poolc[(g0 + slot) * 25 + c], val);
        }
    }
}

// ---------------- final MLP: one block per graph ----------------
__global__ __launch_bounds__(128) void mlp_kernel(
    const float* __restrict__ poolc,
    const float* __restrict__ gf,
    const float* __restrict__ gfW1, const float* __restrict__ gfb1,
    const float* __restrict__ gfW2, const float* __restrict__ gfb2,
    const float* __restrict__ W1, const float* __restrict__ b1,
    const float* __restrict__ W2, const float* __restrict__ b2,
    const float* __restrict__ W3, const float* __restrict__ b3,
    float* __restrict__ out)
{
    int g = blockIdx.x;
    int t = threadIdx.x;
    __shared__ float z[36];
    __shared__ float g1[12];
    __shared__ float h1[128];
    __shared__ float h2[128];
    __shared__ float wsum[2];

    if (t < 12) {
        float a = gfb1[t];
        #pragma unroll
        for (int j = 0; j < 6; j++) a += gf[g * 6 + j] * gfW1[j * 12 + t];
        g1[t] = fmaxf(a, 0.f);
    }
    if (t < 24) {
        float c = fmaxf(poolc[g * 25 + 24], 1.f);
        z[t] = poolc[g * 25 + t] / c;
    }
    __syncthreads();
    if (t < 12) {
        float a = gfb2[t];
        #pragma unroll
        for (int j = 0; j < 12; j++) a += g1[j] * gfW2[j * 12 + t];
        z[24 + t] = fmaxf(a, 0.f);
    }
    __syncthreads();
    {
        float a = b1[t];
        #pragma unroll
        for (int j = 0; j < 36; j++) a += z[j] * W1[j * 128 + t];
        h1[t] = fmaxf(a, 0.f);
    }
    __syncthreads();
    {
        float a = b2[t];
        for (int j = 0; j < 128; j++) a += h1[j] * W2[j * 128 + t];
        h2[t] = fmaxf(a, 0.f);
    }
    __syncthreads();
    float p = h2[t] * W3[t];
    for (int off = 32; off; off >>= 1) p += __shfl_down(p, off);
    if ((t & 63) == 0) wsum[t >> 6] = p;
    __syncthreads();
    if (t == 0) out[g] = wsum[0] + wsum[1] + b3[0];
}

// ---------------- launch ----------------
extern "C" void kernel_launch(void* const* d_in, const int* in_sizes, int n_in,
                              void* d_out, int out_size, void* d_ws, size_t ws_size,
                              hipStream_t stream)
{
    const float* x     = (const float*)d_in[0];
    const int*   ei    = (const int*)d_in[1];
    const int*   batch = (const int*)d_in[2];
    const float* gf    = (const float*)d_in[3];
    const float* Wq    = (const float*)d_in[4];
    const float* bq    = (const float*)d_in[5];
    const float* Wk    = (const float*)d_in[6];
    const float* bk    = (const float*)d_in[7];
    const float* Wv    = (const float*)d_in[8];
    const float* bv    = (const float*)d_in[9];
    const float* Ws    = (const float*)d_in[10];
    const float* bs    = (const float*)d_in[11];
    const float* gfW1  = (const float*)d_in[12];
    const float* gfb1  = (const float*)d_in[13];
    const float* gfW2  = (const float*)d_in[14];
    const float* gfb2  = (const float*)d_in[15];
    const float* W1    = (const float*)d_in[16];
    const float* b1    = (const float*)d_in[17];
    const float* W2    = (const float*)d_in[18];
    const float* b2    = (const float*)d_in[19];
    const float* W3    = (const float*)d_in[20];
    const float* b3    = (const float*)d_in[21];
    float* out = (float*)d_out;

    const int* esrc = ei;
    const int* edst = ei + N_EDGES;

    // workspace layout
    char* ws = (char*)d_ws;
    size_t off = 0;
    auto alloc = [&](size_t bytes) -> void* {
        void* p = ws + off;
        off = (off + bytes + 255) & ~(size_t)255;
        return p;
    };
    __half* kv   = (__half*)alloc((size_t)N_NODES * KVROW * 2);
    float* hA    = (float*)alloc((size_t)N_NODES * DCH * 4);
    float* hB    = (float*)alloc((size_t)N_NODES * DCH * 4);
    int* row_start   = (int*)alloc(((size_t)N_NODES + 1) * 4);
    int* csr_src     = (int*)alloc((size_t)N_EDGES * 4);
    unsigned int* bucket = (unsigned int*)alloc((size_t)NBINS * CAP * 4);
    int* bin_base    = (int*)alloc((size_t)(NBINS + 1) * 4);
    int* bin_cursor  = (int*)alloc((size_t)NBINS_P * 4);
    float* poolc     = (float*)alloc((size_t)N_GRAPHS * 25 * 4);

    const int NB_NODE = (N_NODES + 255) / 256;
    const int NB_ATTN = N_NODES / 32;  // 3125, exact

    // ---- CSR build: slack-bin bucket sort (512-node bins) ----
    cursor_init_kernel<<<1, 256, 0, stream>>>(bin_cursor);
    partition_kernel<<<NB_PART, 512, 0, stream>>>(esrc, edst, bin_cursor, bucket);
    bin_scan_kernel<<<1, 256, 0, stream>>>(bin_cursor, bin_base, row_start);
    bin_scatter_kernel<<<NBINS, 512, 0, stream>>>(bucket, bin_cursor, bin_base, row_start, csr_src);

    hipMemsetAsync(poolc, 0, (size_t)N_GRAPHS * 25 * 4, stream);

    // ---- layers (attn computes q/skip in-kernel; layer 3 fuses pooling) ----
    const float* hin = x;
    float* hbuf[2] = {hA, hB};
    for (int l = 0; l < NLAYERS; l++) {
        kv_kernel<<<NB_NODE, 256, 0, stream>>>(
            hin, Wk + l * 576, bk + l * 24, Wv + l * 576, bv + l * 24, kv);
        if (l < NLAYERS - 1) {
            float* hout = hbuf[l & 1];
            attn_kernel<0><<<NB_ATTN, 256, 0, stream>>>(
                hin, kv, Wq + l * 576, bq + l * 24, Ws + l * 576, bs + l * 24,
                row_start, csr_src, batch, hout, nullptr);
            hin = hout;
        } else {
            attn_kernel<1><<<NB_ATTN, 256, 0, stream>>>(
                hin, kv, Wq + l * 576, bq + l * 24, Ws + l * 576, bs + l * 24,
                row_start, csr_src, batch, nullptr, poolc);
        }
    }

    // ---- MLP ----
    mlp_kernel<<<N_GRAPHS, 128, 0, stream>>>(
        poolc, gf, gfW1, gfb1, gfW2, gfb2, W1, b1, W2, b2, W3, b3, out);
}

// Round 10
// 377.558 us; speedup vs baseline: 1.0772x; 1.0772x over previous
//
#include <hip/hip_runtime.h>
#include <hip/hip_fp16.h>
#include <math.h>

#define N_NODES  100000
#define N_EDGES  3200000
#define N_GRAPHS 512
#define DCH      24
#define NLAYERS  4

// 512 nodes per bin -> 196 bins; bucket entry = (node&511)<<17 | src(17b)
#define BINSHIFT 9
#define BINSZ    512
#define NBINS    196      // ceil(100000 / 512)
#define NBINS_P  200
#define CAP      17408    // mean 16384, sigma 128; +8 sigma
#define EPB      8000     // edges per partition block
#define NB_PART  400

// kv row: 64 halves (128 B, 1 cache line). k at [0:24), v at [24:48), rest pad.
#define KVROW    64

// ---------------- linear kernel: q(f32), kv(f16 packed), skip(f32) ----------------
__global__ __launch_bounds__(256) void lin_kernel(
    const float* __restrict__ h,
    const float* __restrict__ Wq, const float* __restrict__ bq,
    const float* __restrict__ Wk, const float* __restrict__ bk,
    const float* __restrict__ Wv, const float* __restrict__ bv,
    const float* __restrict__ Ws, const float* __restrict__ bs,
    float* __restrict__ q, __half* __restrict__ kv, float* __restrict__ skip)
{
    __shared__ float sW[4 * 576];
    __shared__ float sb[4 * 24];
    for (int i = threadIdx.x; i < 576; i += blockDim.x) {
        sW[0 * 576 + i] = Wq[i];
        sW[1 * 576 + i] = Wk[i];
        sW[2 * 576 + i] = Wv[i];
        sW[3 * 576 + i] = Ws[i];
    }
    if (threadIdx.x < 24) {
        sb[0 * 24 + threadIdx.x] = bq[threadIdx.x];
        sb[1 * 24 + threadIdx.x] = bk[threadIdx.x];
        sb[2 * 24 + threadIdx.x] = bv[threadIdx.x];
        sb[3 * 24 + threadIdx.x] = bs[threadIdx.x];
    }
    __syncthreads();

    int node = blockIdx.x * blockDim.x + threadIdx.x;
    if (node >= N_NODES) return;

    float hx[24];
    const float4* hp = (const float4*)(h + (size_t)node * DCH);
    #pragma unroll
    for (int t = 0; t < 6; t++) {
        float4 f = hp[t];
        hx[4*t] = f.x; hx[4*t+1] = f.y; hx[4*t+2] = f.z; hx[4*t+3] = f.w;
    }

    #pragma unroll
    for (int mtx = 0; mtx < 4; mtx++) {
        float o[24];
        #pragma unroll
        for (int c = 0; c < 24; c++) o[c] = sb[mtx * 24 + c];
        #pragma unroll
        for (int ci = 0; ci < 24; ci++) {
            float hv = hx[ci];
            #pragma unroll
            for (int c = 0; c < 24; c++)
                o[c] += hv * sW[mtx * 576 + ci * 24 + c];
        }
        if (mtx == 0 || mtx == 3) {
            float* dst = (mtx == 0) ? (q + (size_t)node * DCH)
                                    : (skip + (size_t)node * DCH);
            float4* op = (float4*)dst;
            #pragma unroll
            for (int t = 0; t < 6; t++) {
                float4 f;
                f.x = o[4*t]; f.y = o[4*t+1]; f.z = o[4*t+2]; f.w = o[4*t+3];
                op[t] = f;
            }
        } else {
            __half tmp[24];
            #pragma unroll
            for (int c = 0; c < 24; c++) tmp[c] = __float2half_rn(o[c]);
            // k at row offset 0, v at row offset 24 halves (48 B, 16B-aligned)
            float4* op = (float4*)(kv + (size_t)node * KVROW + (mtx == 1 ? 0 : 24));
            const float4* tp = (const float4*)tmp;
            #pragma unroll
            for (int t = 0; t < 3; t++) op[t] = tp[t];
        }
    }
}

// ---------------- CSR build: slack-bin bucket sort, 512-node bins ----------------
__global__ void cursor_init_kernel(int* __restrict__ cursor)
{
    int t = blockIdx.x * 256 + threadIdx.x;
    if (t < NBINS) cursor[t] = t * CAP;
}

__global__ __launch_bounds__(512) void partition_kernel(
    const int* __restrict__ esrc, const int* __restrict__ edst,
    int* __restrict__ cursor, unsigned int* __restrict__ bucket)
{
    __shared__ int hist[NBINS_P];
    __shared__ int base[NBINS_P];
    for (int t = threadIdx.x; t < NBINS_P; t += 512) hist[t] = 0;
    __syncthreads();
    int e0 = blockIdx.x * EPB;
    int e1 = min(e0 + EPB, N_EDGES);
    for (int e = e0 + threadIdx.x; e < e1; e += 512)
        atomicAdd(&hist[edst[e] >> BINSHIFT], 1);
    __syncthreads();
    for (int t = threadIdx.x; t < NBINS; t += 512) {
        int hcount = hist[t];
        base[t] = hcount ? atomicAdd(&cursor[t], hcount) : 0;
    }
    __syncthreads();
    for (int t = threadIdx.x; t < NBINS_P; t += 512) hist[t] = 0;
    __syncthreads();
    for (int e = e0 + threadIdx.x; e < e1; e += 512) {
        int d = edst[e];
        int b = d >> BINSHIFT;
        int lc = atomicAdd(&hist[b], 1);
        int pos = base[b] + lc;
        if (pos < (b + 1) * CAP)  // overflow guard (never fires for uniform input)
            bucket[pos] = ((unsigned)(d & (BINSZ - 1)) << 17) | (unsigned)esrc[e];
    }
}

__global__ __launch_bounds__(256) void bin_scan_kernel(
    const int* __restrict__ cursor,
    int* __restrict__ bin_base, int* __restrict__ row_start)
{
    __shared__ int sd[256];
    int t = threadIdx.x;
    int v = 0;
    if (t < NBINS) v = min(cursor[t] - t * CAP, CAP);
    sd[t] = v;
    __syncthreads();
    for (int off = 1; off < 256; off <<= 1) {
        int u = (t >= off) ? sd[t - off] : 0;
        __syncthreads();
        sd[t] += u;
        __syncthreads();
    }
    if (t < NBINS) bin_base[t] = sd[t] - v;  // exclusive prefix
    if (t == 0) { bin_base[NBINS] = N_EDGES; row_start[N_NODES] = N_EDGES; }
}

__global__ __launch_bounds__(512) void bin_scatter_kernel(
    const unsigned int* __restrict__ bucket, const int* __restrict__ cursor,
    const int* __restrict__ bin_base,
    int* __restrict__ row_start, int* __restrict__ csr_src)
{
    int b = blockIdx.x;
    int node0 = b << BINSHIFT;
    int nn = min(BINSZ, N_NODES - node0);
    int ebeg = b * CAP;
    int cnt  = min(cursor[b] - b * CAP, CAP);
    int obase = bin_base[b];
    __shared__ int c0[BINSZ], s[BINSZ], cur[BINSZ];
    int tid = threadIdx.x;
    c0[tid] = 0;
    __syncthreads();
    for (int i = tid; i < cnt; i += 512)
        atomicAdd(&c0[bucket[ebeg + i] >> 17], 1);
    __syncthreads();
    s[tid] = c0[tid];
    __syncthreads();
    for (int off = 1; off < 512; off <<= 1) {
        int u = (tid >= off) ? s[tid - off] : 0;
        __syncthreads();
        s[tid] += u;
        __syncthreads();
    }
    if (tid < nn) {
        int ex = obase + s[tid] - c0[tid];
        row_start[node0 + tid] = ex;
        cur[tid] = ex;
    }
    __syncthreads();
    for (int i = tid; i < cnt; i += 512) {
        unsigned p = bucket[ebeg + i];
        int j = p >> 17;
        int pos = atomicAdd(&cur[j], 1);
        csr_src[pos] = (int)(p & 0x1FFFF);
    }
}

// ---------------- attention: 8 lanes per dst node, fp16 kv (1 line/edge) ----------
// DO_POOL=1 (last layer): instead of writing out, accumulate graph mean-pool.
#define LPN 8  // lanes per node
template<int DO_POOL>
__global__ __launch_bounds__(256) void attn_kernel(
    const float* __restrict__ q, const __half* __restrict__ kv,
    const float* __restrict__ skip,
    const int* __restrict__ row_start,
    const int* __restrict__ csr_src,
    const int* __restrict__ batch,
    float* __restrict__ out, float* __restrict__ poolc)
{
    __shared__ float spool[8][25];   // only used when DO_POOL
    int node0 = blockIdx.x * (256 / LPN);
    if (DO_POOL) {
        for (int t = threadIdx.x; t < 8 * 25; t += 256) ((float*)spool)[t] = 0.f;
        __syncthreads();
    }

    int i   = node0 + (threadIdx.x >> 3);
    int sub = threadIdx.x & (LPN - 1);
    if (i >= N_NODES) return;

    float qr[24];
    const float4* qp = (const float4*)(q + (size_t)i * DCH);
    #pragma unroll
    for (int t = 0; t < 6; t++) {
        float4 f = qp[t];
        qr[4*t] = f.x; qr[4*t+1] = f.y; qr[4*t+2] = f.z; qr[4*t+3] = f.w;
    }

    float m = -INFINITY, s = 0.f;
    float acc[24];
    #pragma unroll
    for (int c = 0; c < 24; c++) acc[c] = 0.f;

    int beg = row_start[i];
    int end = row_start[i + 1];
    const float scale = 0.2041241452319315f;  // 1/sqrt(24)

    int src_next = (beg + sub < end) ? csr_src[beg + sub] : 0;
    for (int e = beg + sub; e < end; e += LPN) {
        int src = src_next;
        src_next = (e + LPN < end) ? csr_src[e + LPN] : 0;

        const float4* kvp = (const float4*)(kv + (size_t)src * KVROW);
        float4 kr[3], vr[3];
        #pragma unroll
        for (int t = 0; t < 3; t++) kr[t] = kvp[t];
        #pragma unroll
        for (int t = 0; t < 3; t++) vr[t] = kvp[3 + t];

        const __half2* kh = (const __half2*)kr;
        float dot = 0.f;
        #pragma unroll
        for (int j = 0; j < 12; j++) {
            float2 f = __half22float2(kh[j]);
            dot += qr[2*j] * f.x + qr[2*j+1] * f.y;
        }
        dot *= scale;

        float mn   = fmaxf(m, dot);
        float wold = __expf(m - mn);   // first iter: exp(-inf)=0
        float w    = __expf(dot - mn);
        s = s * wold + w;
        const __half2* vh = (const __half2*)vr;
        #pragma unroll
        for (int j = 0; j < 12; j++) {
            float2 f = __half22float2(vh[j]);
            acc[2*j]   = acc[2*j]   * wold + w * f.x;
            acc[2*j+1] = acc[2*j+1] * wold + w * f.y;
        }
        m = mn;
    }

    // merge the LPN lanes' online-softmax states (butterfly within the 8-lane group)
    #pragma unroll
    for (int off = 1; off < LPN; off <<= 1) {
        float m2 = __shfl_xor(m, off);
        float s2 = __shfl_xor(s, off);
        float mn = fmaxf(m, m2);
        float w1 = (m  == mn) ? 1.f : __expf(m  - mn);  // avoids (-inf)-(-inf)=NaN
        float w2 = (m2 == mn) ? 1.f : __expf(m2 - mn);
        s = s * w1 + s2 * w2;
        #pragma unroll
        for (int c = 0; c < 24; c++) {
            float a2 = __shfl_xor(acc[c], off);
            acc[c] = acc[c] * w1 + a2 * w2;
        }
        m = mn;
    }

    if (!DO_POOL) {
        if (sub == 0) {
            float inv = 1.f / (s + 1e-16f);
            const float4* sp = (const float4*)(skip + (size_t)i * DCH);
            float4* op = (float4*)(out + (size_t)i * DCH);
            #pragma unroll
            for (int t = 0; t < 6; t++) {
                float4 sk = sp[t];
                float4 r;
                r.x = fmaxf(sk.x + acc[4*t]   * inv, 0.f);
                r.y = fmaxf(sk.y + acc[4*t+1] * inv, 0.f);
                r.z = fmaxf(sk.z + acc[4*t+2] * inv, 0.f);
                r.w = fmaxf(sk.w + acc[4*t+3] * inv, 0.f);
                op[t] = r;
            }
        }
    } else {
        // every lane holds merged state; lane sub handles channels 3sub..3sub+2
        float inv = 1.f / (s + 1e-16f);
        const float* sp = skip + (size_t)i * DCH + 3 * sub;
        float o0 = fmaxf(sp[0] + acc[3*sub]     * inv, 0.f);
        float o1 = fmaxf(sp[1] + acc[3*sub + 1] * inv, 0.f);
        float o2 = fmaxf(sp[2] + acc[3*sub + 2] * inv, 0.f);
        int g  = batch[i];
        int g0 = batch[node0];
        int rel = g - g0;
        if (rel < 8) {
            atomicAdd(&spool[rel][3*sub],     o0);
            atomicAdd(&spool[rel][3*sub + 1], o1);
            atomicAdd(&spool[rel][3*sub + 2], o2);
            if (sub == 0) atomicAdd(&spool[rel][24], 1.f);
        } else {
            atomicAdd(&poolc[g * 25 + 3*sub],     o0);
            atomicAdd(&poolc[g * 25 + 3*sub + 1], o1);
            atomicAdd(&poolc[g * 25 + 3*sub + 2], o2);
            if (sub == 0) atomicAdd(&poolc[g * 25 + 24], 1.f);
        }
        __syncthreads();
        int g0b = batch[node0];
        for (int t = threadIdx.x; t < 8 * 25; t += 256) {
            int slot = t / 25, c = t % 25;
            float val = spool[slot][c];
            if (val != 0.f)
                atomicAdd(&poolc[(g0b + slot) * 25 + c], val);
        }
    }
}

// ---------------- final MLP: one block per graph ----------------
__global__ __launch_bounds__(128) void mlp_kernel(
    const float* __restrict__ poolc,
    const float* __restrict__ gf,
    const float* __restrict__ gfW1, const float* __restrict__ gfb1,
    const float* __restrict__ gfW2, const float* __restrict__ gfb2,
    const float* __restrict__ W1, const float* __restrict__ b1,
    const float* __restrict__ W2, const float* __restrict__ b2,
    const float* __restrict__ W3, const float* __restrict__ b3,
    float* __restrict__ out)
{
    int g = blockIdx.x;
    int t = threadIdx.x;
    __shared__ float z[36];
    __shared__ float g1[12];
    __shared__ float h1[128];
    __shared__ float h2[128];
    __shared__ float wsum[2];

    if (t < 12) {
        float a = gfb1[t];
        #pragma unroll
        for (int j = 0; j < 6; j++) a += gf[g * 6 + j] * gfW1[j * 12 + t];
        g1[t] = fmaxf(a, 0.f);
    }
    if (t < 24) {
        float c = fmaxf(poolc[g * 25 + 24], 1.f);
        z[t] = poolc[g * 25 + t] / c;
    }
    __syncthreads();
    if (t < 12) {
        float a = gfb2[t];
        #pragma unroll
        for (int j = 0; j < 12; j++) a += g1[j] * gfW2[j * 12 + t];
        z[24 + t] = fmaxf(a, 0.f);
    }
    __syncthreads();
    {
        float a = b1[t];
        #pragma unroll
        for (int j = 0; j < 36; j++) a += z[j] * W1[j * 128 + t];
        h1[t] = fmaxf(a, 0.f);
    }
    __syncthreads();
    {
        float a = b2[t];
        for (int j = 0; j < 128; j++) a += h1[j] * W2[j * 128 + t];
        h2[t] = fmaxf(a, 0.f);
    }
    __syncthreads();
    float p = h2[t] * W3[t];
    for (int off = 32; off; off >>= 1) p += __shfl_down(p, off);
    if ((t & 63) == 0) wsum[t >> 6] = p;
    __syncthreads();
    if (t == 0) out[g] = wsum[0] + wsum[1] + b3[0];
}

// ---------------- launch ----------------
extern "C" void kernel_launch(void* const* d_in, const int* in_sizes, int n_in,
                              void* d_out, int out_size, void* d_ws, size_t ws_size,
                              hipStream_t stream)
{
    const float* x     = (const float*)d_in[0];
    const int*   ei    = (const int*)d_in[1];
    const int*   batch = (const int*)d_in[2];
    const float* gf    = (const float*)d_in[3];
    const float* Wq    = (const float*)d_in[4];
    const float* bq    = (const float*)d_in[5];
    const float* Wk    = (const float*)d_in[6];
    const float* bk    = (const float*)d_in[7];
    const float* Wv    = (const float*)d_in[8];
    const float* bv    = (const float*)d_in[9];
    const float* Ws    = (const float*)d_in[10];
    const float* bs    = (const float*)d_in[11];
    const float* gfW1  = (const float*)d_in[12];
    const float* gfb1  = (const float*)d_in[13];
    const float* gfW2  = (const float*)d_in[14];
    const float* gfb2  = (const float*)d_in[15];
    const float* W1    = (const float*)d_in[16];
    const float* b1    = (const float*)d_in[17];
    const float* W2    = (const float*)d_in[18];
    const float* b2    = (const float*)d_in[19];
    const float* W3    = (const float*)d_in[20];
    const float* b3    = (const float*)d_in[21];
    float* out = (float*)d_out;

    const int* esrc = ei;
    const int* edst = ei + N_EDGES;

    // workspace layout
    char* ws = (char*)d_ws;
    size_t off = 0;
    auto alloc = [&](size_t bytes) -> void* {
        void* p = ws + off;
        off = (off + bytes + 255) & ~(size_t)255;
        return p;
    };
    float* q     = (float*)alloc((size_t)N_NODES * DCH * 4);
    __half* kv   = (__half*)alloc((size_t)N_NODES * KVROW * 2);
    float* hA    = (float*)alloc((size_t)N_NODES * DCH * 4);
    float* hB    = (float*)alloc((size_t)N_NODES * DCH * 4);
    float* skipb = (float*)alloc((size_t)N_NODES * DCH * 4);
    int* row_start   = (int*)alloc(((size_t)N_NODES + 1) * 4);
    int* csr_src     = (int*)alloc((size_t)N_EDGES * 4);
    unsigned int* bucket = (unsigned int*)alloc((size_t)NBINS * CAP * 4);
    int* bin_base    = (int*)alloc((size_t)(NBINS + 1) * 4);
    int* bin_cursor  = (int*)alloc((size_t)NBINS_P * 4);
    float* poolc     = (float*)alloc((size_t)N_GRAPHS * 25 * 4);

    const int NB_NODE = (N_NODES + 255) / 256;
    const int NB_ATTN = (N_NODES * LPN + 255) / 256;  // 3125 exact

    // ---- CSR build: slack-bin bucket sort (512-node bins) ----
    cursor_init_kernel<<<1, 256, 0, stream>>>(bin_cursor);
    partition_kernel<<<NB_PART, 512, 0, stream>>>(esrc, edst, bin_cursor, bucket);
    bin_scan_kernel<<<1, 256, 0, stream>>>(bin_cursor, bin_base, row_start);
    bin_scatter_kernel<<<NBINS, 512, 0, stream>>>(bucket, bin_cursor, bin_base, row_start, csr_src);

    hipMemsetAsync(poolc, 0, (size_t)N_GRAPHS * 25 * 4, stream);

    // ---- layers; layer 3 fuses mean-pool into attn ----
    const float* hin = x;
    float* hbuf[2] = {hA, hB};
    for (int l = 0; l < NLAYERS; l++) {
        float* hout = (l < NLAYERS - 1) ? hbuf[l & 1] : nullptr;
        float* sk   = (l < NLAYERS - 1) ? hout : skipb;  // layer<3: skip written into hout? NO
        // NOTE: skip must be its own buffer since attn reads it after writing out rows;
        // use skipb for all layers (attn<0> reads skip and writes hout separately).
        lin_kernel<<<NB_NODE, 256, 0, stream>>>(
            hin, Wq + l * 576, bq + l * 24, Wk + l * 576, bk + l * 24,
            Wv + l * 576, bv + l * 24, Ws + l * 576, bs + l * 24,
            q, kv, skipb);
        if (l < NLAYERS - 1) {
            attn_kernel<0><<<NB_ATTN, 256, 0, stream>>>(
                q, kv, skipb, row_start, csr_src, batch, hout, nullptr);
            hin = hout;
        } else {
            attn_kernel<1><<<NB_ATTN, 256, 0, stream>>>(
                q, kv, skipb, row_start, csr_src, batch, nullptr, poolc);
        }
    }

    // ---- MLP ----
    mlp_kernel<<<N_GRAPHS, 128, 0, stream>>>(
        poolc, gf, gfW1, gfb1, gfW2, gfb2, W1, b1, W2, b2, W3, b3, out);
}

// Round 11
// 351.613 us; speedup vs baseline: 1.1567x; 1.0738x over previous
//
#include <hip/hip_runtime.h>
#include <hip/hip_fp16.h>
#include <math.h>

#define N_NODES  100000
#define N_EDGES  3200000
#define N_GRAPHS 512
#define DCH      24
#define NLAYERS  4

// 512 nodes per bin -> 196 bins; bucket entry = (node&511)<<17 | src(17b)
#define BINSHIFT 9
#define BINSZ    512
#define NBINS    196      // ceil(100000 / 512)
#define NBINS_P  200
#define CAP      17408    // mean 16384, sigma 128; +8 sigma
#define EPB      8000     // edges per partition block
#define NB_PART  400

// kv row: 64 halves (128 B, 1 cache line). k at [0:24), v at [24:48), rest pad.
#define KVROW    64

// ---------------- linear kernel (layer 0 only): q(f32), kv(f16), skip(f32) ----------------
__global__ __launch_bounds__(256) void lin_kernel(
    const float* __restrict__ h,
    const float* __restrict__ Wq, const float* __restrict__ bq,
    const float* __restrict__ Wk, const float* __restrict__ bk,
    const float* __restrict__ Wv, const float* __restrict__ bv,
    const float* __restrict__ Ws, const float* __restrict__ bs,
    float* __restrict__ q, __half* __restrict__ kv, float* __restrict__ skip)
{
    __shared__ float sW[4 * 576];
    __shared__ float sb[4 * 24];
    for (int i = threadIdx.x; i < 576; i += blockDim.x) {
        sW[0 * 576 + i] = Wq[i];
        sW[1 * 576 + i] = Wk[i];
        sW[2 * 576 + i] = Wv[i];
        sW[3 * 576 + i] = Ws[i];
    }
    if (threadIdx.x < 24) {
        sb[0 * 24 + threadIdx.x] = bq[threadIdx.x];
        sb[1 * 24 + threadIdx.x] = bk[threadIdx.x];
        sb[2 * 24 + threadIdx.x] = bv[threadIdx.x];
        sb[3 * 24 + threadIdx.x] = bs[threadIdx.x];
    }
    __syncthreads();

    int node = blockIdx.x * blockDim.x + threadIdx.x;
    if (node >= N_NODES) return;

    float hx[24];
    const float4* hp = (const float4*)(h + (size_t)node * DCH);
    #pragma unroll
    for (int t = 0; t < 6; t++) {
        float4 f = hp[t];
        hx[4*t] = f.x; hx[4*t+1] = f.y; hx[4*t+2] = f.z; hx[4*t+3] = f.w;
    }

    #pragma unroll
    for (int mtx = 0; mtx < 4; mtx++) {
        float o[24];
        #pragma unroll
        for (int c = 0; c < 24; c++) o[c] = sb[mtx * 24 + c];
        #pragma unroll
        for (int ci = 0; ci < 24; ci++) {
            float hv = hx[ci];
            #pragma unroll
            for (int c = 0; c < 24; c++)
                o[c] += hv * sW[mtx * 576 + ci * 24 + c];
        }
        if (mtx == 0 || mtx == 3) {
            float* dst = (mtx == 0) ? (q + (size_t)node * DCH)
                                    : (skip + (size_t)node * DCH);
            float4* op = (float4*)dst;
            #pragma unroll
            for (int t = 0; t < 6; t++) {
                float4 f;
                f.x = o[4*t]; f.y = o[4*t+1]; f.z = o[4*t+2]; f.w = o[4*t+3];
                op[t] = f;
            }
        } else {
            __half tmp[24];
            #pragma unroll
            for (int c = 0; c < 24; c++) tmp[c] = __float2half_rn(o[c]);
            float4* op = (float4*)(kv + (size_t)node * KVROW + (mtx == 1 ? 0 : 24));
            const float4* tp = (const float4*)tmp;
            #pragma unroll
            for (int t = 0; t < 3; t++) op[t] = tp[t];
        }
    }
}

// ---------------- CSR build: slack-bin bucket sort, 512-node bins ----------------
__global__ void cursor_init_kernel(int* __restrict__ cursor)
{
    int t = blockIdx.x * 256 + threadIdx.x;
    if (t < NBINS) cursor[t] = t * CAP;
}

__global__ __launch_bounds__(512) void partition_kernel(
    const int* __restrict__ esrc, const int* __restrict__ edst,
    int* __restrict__ cursor, unsigned int* __restrict__ bucket)
{
    __shared__ int hist[NBINS_P];
    __shared__ int base[NBINS_P];
    for (int t = threadIdx.x; t < NBINS_P; t += 512) hist[t] = 0;
    __syncthreads();
    int e0 = blockIdx.x * EPB;
    int e1 = min(e0 + EPB, N_EDGES);
    for (int e = e0 + threadIdx.x; e < e1; e += 512)
        atomicAdd(&hist[edst[e] >> BINSHIFT], 1);
    __syncthreads();
    for (int t = threadIdx.x; t < NBINS; t += 512) {
        int hcount = hist[t];
        base[t] = hcount ? atomicAdd(&cursor[t], hcount) : 0;
    }
    __syncthreads();
    for (int t = threadIdx.x; t < NBINS_P; t += 512) hist[t] = 0;
    __syncthreads();
    for (int e = e0 + threadIdx.x; e < e1; e += 512) {
        int d = edst[e];
        int b = d >> BINSHIFT;
        int lc = atomicAdd(&hist[b], 1);
        int pos = base[b] + lc;
        if (pos < (b + 1) * CAP)  // overflow guard (never fires for uniform input)
            bucket[pos] = ((unsigned)(d & (BINSZ - 1)) << 17) | (unsigned)esrc[e];
    }
}

__global__ __launch_bounds__(256) void bin_scan_kernel(
    const int* __restrict__ cursor,
    int* __restrict__ bin_base, int* __restrict__ row_start)
{
    __shared__ int sd[256];
    int t = threadIdx.x;
    int v = 0;
    if (t < NBINS) v = min(cursor[t] - t * CAP, CAP);
    sd[t] = v;
    __syncthreads();
    for (int off = 1; off < 256; off <<= 1) {
        int u = (t >= off) ? sd[t - off] : 0;
        __syncthreads();
        sd[t] += u;
        __syncthreads();
    }
    if (t < NBINS) bin_base[t] = sd[t] - v;  // exclusive prefix
    if (t == 0) { bin_base[NBINS] = N_EDGES; row_start[N_NODES] = N_EDGES; }
}

__global__ __launch_bounds__(512) void bin_scatter_kernel(
    const unsigned int* __restrict__ bucket, const int* __restrict__ cursor,
    const int* __restrict__ bin_base,
    int* __restrict__ row_start, int* __restrict__ csr_src)
{
    int b = blockIdx.x;
    int node0 = b << BINSHIFT;
    int nn = min(BINSZ, N_NODES - node0);
    int ebeg = b * CAP;
    int cnt  = min(cursor[b] - b * CAP, CAP);
    int obase = bin_base[b];
    __shared__ int c0[BINSZ], s[BINSZ], cur[BINSZ];
    int tid = threadIdx.x;
    c0[tid] = 0;
    __syncthreads();
    for (int i = tid; i < cnt; i += 512)
        atomicAdd(&c0[bucket[ebeg + i] >> 17], 1);
    __syncthreads();
    s[tid] = c0[tid];
    __syncthreads();
    for (int off = 1; off < 512; off <<= 1) {
        int u = (tid >= off) ? s[tid - off] : 0;
        __syncthreads();
        s[tid] += u;
        __syncthreads();
    }
    if (tid < nn) {
        int ex = obase + s[tid] - c0[tid];
        row_start[node0 + tid] = ex;
        cur[tid] = ex;
    }
    __syncthreads();
    for (int i = tid; i < cnt; i += 512) {
        unsigned p = bucket[ebeg + i];
        int j = p >> 17;
        int pos = atomicAdd(&cur[j], 1);
        csr_src[pos] = (int)(p & 0x1FFFF);
    }
}

// ---------------- fused attention ----------------
// MODE 0: tail-fuse next layer's linear (q/kv/skip) after the gather+merge.
//         Weight LDS load issues at kernel start; barrier only AFTER gather loop,
//         so the gather engine runs uninterrupted (r9 lesson: no front coupling).
// MODE 1: last layer; epilogue accumulates graph mean-pool.
// Grid is exactly N_NODES/32 blocks (100000 % 32 == 0) -> no bounds branch, barrier-safe.
#define LPN 8
template<int MODE>
__global__ __launch_bounds__(256) void attn_fused(
    const float* __restrict__ q, const __half* __restrict__ kv,
    const float* __restrict__ skip,
    const int* __restrict__ row_start, const int* __restrict__ csr_src,
    const float* __restrict__ Wqn, const float* __restrict__ bqn,
    const float* __restrict__ Wkn, const float* __restrict__ bkn,
    const float* __restrict__ Wvn, const float* __restrict__ bvn,
    const float* __restrict__ Wsn, const float* __restrict__ bsn,
    float* __restrict__ qn, __half* __restrict__ kvn, float* __restrict__ skipn,
    const int* __restrict__ batch, float* __restrict__ poolc)
{
    __shared__ float sW[4 * 576];
    __shared__ float sb[4 * 24];
    __shared__ float spool[8][25];

    int tid = threadIdx.x;
    int node0 = blockIdx.x * 32;

    if (MODE == 0) {
        // issue next-layer weight loads now; not consumed until after gather loop
        for (int t = tid; t < 576; t += 256) {
            sW[t]        = Wqn[t];
            sW[576 + t]  = Wkn[t];
            sW[1152 + t] = Wvn[t];
            sW[1728 + t] = Wsn[t];
        }
        if (tid < 24) {
            sb[tid]      = bqn[tid];
            sb[24 + tid] = bkn[tid];
            sb[48 + tid] = bvn[tid];
            sb[72 + tid] = bsn[tid];
        }
    } else {
        for (int t = tid; t < 8 * 25; t += 256) ((float*)spool)[t] = 0.f;
        __syncthreads();
    }

    int i   = node0 + (tid >> 3);
    int sub = tid & (LPN - 1);

    float qr[24];
    const float4* qp = (const float4*)(q + (size_t)i * DCH);
    #pragma unroll
    for (int t = 0; t < 6; t++) {
        float4 f = qp[t];
        qr[4*t] = f.x; qr[4*t+1] = f.y; qr[4*t+2] = f.z; qr[4*t+3] = f.w;
    }

    float m = -INFINITY, s = 0.f;
    float acc[24];
    #pragma unroll
    for (int c = 0; c < 24; c++) acc[c] = 0.f;

    int beg = row_start[i];
    int end = row_start[i + 1];
    const float scale = 0.2041241452319315f;  // 1/sqrt(24)

    int src_next = (beg + sub < end) ? csr_src[beg + sub] : 0;
    for (int e = beg + sub; e < end; e += LPN) {
        int src = src_next;
        src_next = (e + LPN < end) ? csr_src[e + LPN] : 0;

        const float4* kvp = (const float4*)(kv + (size_t)src * KVROW);
        float4 kr[3], vr[3];
        #pragma unroll
        for (int t = 0; t < 3; t++) kr[t] = kvp[t];
        #pragma unroll
        for (int t = 0; t < 3; t++) vr[t] = kvp[3 + t];

        const __half2* kh = (const __half2*)kr;
        float dot = 0.f;
        #pragma unroll
        for (int j = 0; j < 12; j++) {
            float2 f = __half22float2(kh[j]);
            dot += qr[2*j] * f.x + qr[2*j+1] * f.y;
        }
        dot *= scale;

        float mn   = fmaxf(m, dot);
        float wold = __expf(m - mn);   // first iter: exp(-inf)=0
        float w    = __expf(dot - mn);
        s = s * wold + w;
        const __half2* vh = (const __half2*)vr;
        #pragma unroll
        for (int j = 0; j < 12; j++) {
            float2 f = __half22float2(vh[j]);
            acc[2*j]   = acc[2*j]   * wold + w * f.x;
            acc[2*j+1] = acc[2*j+1] * wold + w * f.y;
        }
        m = mn;
    }

    // butterfly merge: ALL lanes end with the merged (m, s, acc)
    #pragma unroll
    for (int off = 1; off < LPN; off <<= 1) {
        float m2 = __shfl_xor(m, off);
        float s2 = __shfl_xor(s, off);
        float mn = fmaxf(m, m2);
        float w1 = (m  == mn) ? 1.f : __expf(m  - mn);  // avoids (-inf)-(-inf)=NaN
        float w2 = (m2 == mn) ? 1.f : __expf(m2 - mn);
        s = s * w1 + s2 * w2;
        #pragma unroll
        for (int c = 0; c < 24; c++) {
            float a2 = __shfl_xor(acc[c], off);
            acc[c] = acc[c] * w1 + a2 * w2;
        }
        m = mn;
    }

    if (MODE == 0) {
        __syncthreads();  // weights ready (and issued long ago)
        float inv = 1.f / (s + 1e-16f);
        float hrow[24];
        const float4* sp = (const float4*)(skip + (size_t)i * DCH);
        #pragma unroll
        for (int t = 0; t < 6; t++) {
            float4 f = sp[t];
            hrow[4*t]   = fmaxf(f.x + acc[4*t]   * inv, 0.f);
            hrow[4*t+1] = fmaxf(f.y + acc[4*t+1] * inv, 0.f);
            hrow[4*t+2] = fmaxf(f.z + acc[4*t+2] * inv, 0.f);
            hrow[4*t+3] = fmaxf(f.w + acc[4*t+3] * inv, 0.f);
        }
        int c0 = 3 * sub;
        float oq0 = sb[c0],      oq1 = sb[c0+1],      oq2 = sb[c0+2];
        float ok0 = sb[24+c0],   ok1 = sb[24+c0+1],   ok2 = sb[24+c0+2];
        float ov0 = sb[48+c0],   ov1 = sb[48+c0+1],   ov2 = sb[48+c0+2];
        float os0 = sb[72+c0],   os1 = sb[72+c0+1],   os2 = sb[72+c0+2];
        #pragma unroll
        for (int ci = 0; ci < 24; ci++) {
            float hv = hrow[ci];
            const float* w = &sW[ci * 24 + c0];
            oq0 += hv * w[0];    oq1 += hv * w[1];    oq2 += hv * w[2];
            ok0 += hv * w[576];  ok1 += hv * w[577];  ok2 += hv * w[578];
            ov0 += hv * w[1152]; ov1 += hv * w[1153]; ov2 += hv * w[1154];
            os0 += hv * w[1728]; os1 += hv * w[1729]; os2 += hv * w[1730];
        }
        float* qo = qn + (size_t)i * DCH + c0;
        qo[0] = oq0; qo[1] = oq1; qo[2] = oq2;
        float* so = skipn + (size_t)i * DCH + c0;
        so[0] = os0; so[1] = os1; so[2] = os2;
        __half* kp = kvn + (size_t)i * KVROW + c0;
        kp[0] = __float2half_rn(ok0); kp[1] = __float2half_rn(ok1); kp[2] = __float2half_rn(ok2);
        __half* vp = kvn + (size_t)i * KVROW + 24 + c0;
        vp[0] = __float2half_rn(ov0); vp[1] = __float2half_rn(ov1); vp[2] = __float2half_rn(ov2);
    } else {
        // pool epilogue: lane sub handles channels 3sub..3sub+2
        float inv = 1.f / (s + 1e-16f);
        const float* sp = skip + (size_t)i * DCH + 3 * sub;
        float o0 = fmaxf(sp[0] + acc[3*sub]     * inv, 0.f);
        float o1 = fmaxf(sp[1] + acc[3*sub + 1] * inv, 0.f);
        float o2 = fmaxf(sp[2] + acc[3*sub + 2] * inv, 0.f);
        int g  = batch[i];
        int g0 = batch[node0];
        int rel = g - g0;
        if (rel < 8) {
            atomicAdd(&spool[rel][3*sub],     o0);
            atomicAdd(&spool[rel][3*sub + 1], o1);
            atomicAdd(&spool[rel][3*sub + 2], o2);
            if (sub == 0) atomicAdd(&spool[rel][24], 1.f);
        } else {
            atomicAdd(&poolc[g * 25 + 3*sub],     o0);
            atomicAdd(&poolc[g * 25 + 3*sub + 1], o1);
            atomicAdd(&poolc[g * 25 + 3*sub + 2], o2);
            if (sub == 0) atomicAdd(&poolc[g * 25 + 24], 1.f);
        }
        __syncthreads();
        for (int t = tid; t < 8 * 25; t += 256) {
            int slot = t / 25, c = t % 25;
            float val = spool[slot][c];
            if (val != 0.f)
                atomicAdd(&poolc[(g0 + slot) * 25 + c], val);
        }
    }
}

// ---------------- final MLP: one block per graph ----------------
__global__ __launch_bounds__(128) void mlp_kernel(
    const float* __restrict__ poolc,
    const float* __restrict__ gf,
    const float* __restrict__ gfW1, const float* __restrict__ gfb1,
    const float* __restrict__ gfW2, const float* __restrict__ gfb2,
    const float* __restrict__ W1, const float* __restrict__ b1,
    const float* __restrict__ W2, const float* __restrict__ b2,
    const float* __restrict__ W3, const float* __restrict__ b3,
    float* __restrict__ out)
{
    int g = blockIdx.x;
    int t = threadIdx.x;
    __shared__ float z[36];
    __shared__ float g1[12];
    __shared__ float h1[128];
    __shared__ float h2[128];
    __shared__ float wsum[2];

    if (t < 12) {
        float a = gfb1[t];
        #pragma unroll
        for (int j = 0; j < 6; j++) a += gf[g * 6 + j] * gfW1[j * 12 + t];
        g1[t] = fmaxf(a, 0.f);
    }
    if (t < 24) {
        float c = fmaxf(poolc[g * 25 + 24], 1.f);
        z[t] = poolc[g * 25 + t] / c;
    }
    __syncthreads();
    if (t < 12) {
        float a = gfb2[t];
        #pragma unroll
        for (int j = 0; j < 12; j++) a += g1[j] * gfW2[j * 12 + t];
        z[24 + t] = fmaxf(a, 0.f);
    }
    __syncthreads();
    {
        float a = b1[t];
        #pragma unroll
        for (int j = 0; j < 36; j++) a += z[j] * W1[j * 128 + t];
        h1[t] = fmaxf(a, 0.f);
    }
    __syncthreads();
    {
        float a = b2[t];
        for (int j = 0; j < 128; j++) a += h1[j] * W2[j * 128 + t];
        h2[t] = fmaxf(a, 0.f);
    }
    __syncthreads();
    float p = h2[t] * W3[t];
    for (int off = 32; off; off >>= 1) p += __shfl_down(p, off);
    if ((t & 63) == 0) wsum[t >> 6] = p;
    __syncthreads();
    if (t == 0) out[g] = wsum[0] + wsum[1] + b3[0];
}

// ---------------- launch ----------------
extern "C" void kernel_launch(void* const* d_in, const int* in_sizes, int n_in,
                              void* d_out, int out_size, void* d_ws, size_t ws_size,
                              hipStream_t stream)
{
    const float* x     = (const float*)d_in[0];
    const int*   ei    = (const int*)d_in[1];
    const int*   batch = (const int*)d_in[2];
    const float* gf    = (const float*)d_in[3];
    const float* Wq    = (const float*)d_in[4];
    const float* bq    = (const float*)d_in[5];
    const float* Wk    = (const float*)d_in[6];
    const float* bk    = (const float*)d_in[7];
    const float* Wv    = (const float*)d_in[8];
    const float* bv    = (const float*)d_in[9];
    const float* Ws    = (const float*)d_in[10];
    const float* bs    = (const float*)d_in[11];
    const float* gfW1  = (const float*)d_in[12];
    const float* gfb1  = (const float*)d_in[13];
    const float* gfW2  = (const float*)d_in[14];
    const float* gfb2  = (const float*)d_in[15];
    const float* W1    = (const float*)d_in[16];
    const float* b1    = (const float*)d_in[17];
    const float* W2    = (const float*)d_in[18];
    const float* b2    = (const float*)d_in[19];
    const float* W3    = (const float*)d_in[20];
    const float* b3    = (const float*)d_in[21];
    float* out = (float*)d_out;

    const int* esrc = ei;
    const int* edst = ei + N_EDGES;

    // workspace layout
    char* ws = (char*)d_ws;
    size_t off = 0;
    auto alloc = [&](size_t bytes) -> void* {
        void* p = ws + off;
        off = (off + bytes + 255) & ~(size_t)255;
        return p;
    };
    float*  qA   = (float*)alloc((size_t)N_NODES * DCH * 4);
    __half* kvA  = (__half*)alloc((size_t)N_NODES * KVROW * 2);
    float*  skA  = (float*)alloc((size_t)N_NODES * DCH * 4);
    float*  qB   = (float*)alloc((size_t)N_NODES * DCH * 4);
    float*  skB  = (float*)alloc((size_t)N_NODES * DCH * 4);
    int* row_start   = (int*)alloc(((size_t)N_NODES + 1) * 4);
    int* csr_src     = (int*)alloc((size_t)N_EDGES * 4);
    // bucket (13.65 MB) is dead after bin_scatter; kvB (12.8 MB) aliases it.
    unsigned int* bucket = (unsigned int*)alloc((size_t)NBINS * CAP * 4);
    __half* kvB  = (__half*)bucket;
    int* bin_base    = (int*)alloc((size_t)(NBINS + 1) * 4);
    int* bin_cursor  = (int*)alloc((size_t)NBINS_P * 4);
    float* poolc     = (float*)alloc((size_t)N_GRAPHS * 25 * 4);

    const int NB_NODE = (N_NODES + 255) / 256;
    const int NB_ATTN = N_NODES / 32;  // 3125, exact (100000 % 32 == 0)

    // ---- CSR build: slack-bin bucket sort (512-node bins) ----
    cursor_init_kernel<<<1, 256, 0, stream>>>(bin_cursor);
    partition_kernel<<<NB_PART, 512, 0, stream>>>(esrc, edst, bin_cursor, bucket);
    bin_scan_kernel<<<1, 256, 0, stream>>>(bin_cursor, bin_base, row_start);
    bin_scatter_kernel<<<NBINS, 512, 0, stream>>>(bucket, bin_cursor, bin_base, row_start, csr_src);

    hipMemsetAsync(poolc, 0, (size_t)N_GRAPHS * 25 * 4, stream);

    // ---- layer 0 linear from x ----
    lin_kernel<<<NB_NODE, 256, 0, stream>>>(
        x, Wq, bq, Wk, bk, Wv, bv, Ws, bs, qA, kvA, skA);

    // ---- layers 0..2: attn with tail-fused next-layer linear (ping-pong A/B) ----
    attn_fused<0><<<NB_ATTN, 256, 0, stream>>>(
        qA, kvA, skA, row_start, csr_src,
        Wq + 1*576, bq + 1*24, Wk + 1*576, bk + 1*24,
        Wv + 1*576, bv + 1*24, Ws + 1*576, bs + 1*24,
        qB, kvB, skB, nullptr, nullptr);
    attn_fused<0><<<NB_ATTN, 256, 0, stream>>>(
        qB, kvB, skB, row_start, csr_src,
        Wq + 2*576, bq + 2*24, Wk + 2*576, bk + 2*24,
        Wv + 2*576, bv + 2*24, Ws + 2*576, bs + 2*24,
        qA, kvA, skA, nullptr, nullptr);
    attn_fused<0><<<NB_ATTN, 256, 0, stream>>>(
        qA, kvA, skA, row_start, csr_src,
        Wq + 3*576, bq + 3*24, Wk + 3*576, bk + 3*24,
        Wv + 3*576, bv + 3*24, Ws + 3*576, bs + 3*24,
        qB, kvB, skB, nullptr, nullptr);

    // ---- layer 3: attn with fused mean-pool ----
    attn_fused<1><<<NB_ATTN, 256, 0, stream>>>(
        qB, kvB, skB, row_start, csr_src,
        nullptr, nullptr, nullptr, nullptr, nullptr, nullptr, nullptr, nullptr,
        nullptr, nullptr, nullptr, batch, poolc);

    // ---- MLP ----
    mlp_kernel<<<N_GRAPHS, 128, 0, stream>>>(
        poolc, gf, gfW1, gfb1, gfW2, gfb2, W1, b1, W2, b2, W3, b3, out);
}

// Round 12
// 351.212 us; speedup vs baseline: 1.1580x; 1.0011x over previous
//
#include <hip/hip_runtime.h>
#include <hip/hip_fp16.h>
#include <math.h>

#define N_NODES  100000
#define N_EDGES  3200000
#define N_GRAPHS 512
#define DCH      24
#define NLAYERS  4

// 512 nodes per bin -> 196 bins; bucket entry = (node&511)<<17 | src(17b)
#define BINSHIFT 9
#define BINSZ    512
#define NBINS    196      // ceil(100000 / 512)
#define NBINS_P  200
#define CAP      17408    // mean 16384, sigma 128; +8 sigma
#define EPB      8000     // edges per partition block
#define NB_PART  400

// kv row: 64 halves (128 B, 1 cache line). k at [0:24), v at [24:48), rest pad.
#define KVROW    64

// ---------------- linear kernel (layer 0 only): q(f32), kv(f16), skip(f32) ----------------
__global__ __launch_bounds__(256) void lin_kernel(
    const float* __restrict__ h,
    const float* __restrict__ Wq, const float* __restrict__ bq,
    const float* __restrict__ Wk, const float* __restrict__ bk,
    const float* __restrict__ Wv, const float* __restrict__ bv,
    const float* __restrict__ Ws, const float* __restrict__ bs,
    float* __restrict__ q, __half* __restrict__ kv, float* __restrict__ skip)
{
    __shared__ float sW[4 * 576];
    __shared__ float sb[4 * 24];
    for (int i = threadIdx.x; i < 576; i += blockDim.x) {
        sW[0 * 576 + i] = Wq[i];
        sW[1 * 576 + i] = Wk[i];
        sW[2 * 576 + i] = Wv[i];
        sW[3 * 576 + i] = Ws[i];
    }
    if (threadIdx.x < 24) {
        sb[0 * 24 + threadIdx.x] = bq[threadIdx.x];
        sb[1 * 24 + threadIdx.x] = bk[threadIdx.x];
        sb[2 * 24 + threadIdx.x] = bv[threadIdx.x];
        sb[3 * 24 + threadIdx.x] = bs[threadIdx.x];
    }
    __syncthreads();

    int node = blockIdx.x * blockDim.x + threadIdx.x;
    if (node >= N_NODES) return;

    float hx[24];
    const float4* hp = (const float4*)(h + (size_t)node * DCH);
    #pragma unroll
    for (int t = 0; t < 6; t++) {
        float4 f = hp[t];
        hx[4*t] = f.x; hx[4*t+1] = f.y; hx[4*t+2] = f.z; hx[4*t+3] = f.w;
    }

    #pragma unroll
    for (int mtx = 0; mtx < 4; mtx++) {
        float o[24];
        #pragma unroll
        for (int c = 0; c < 24; c++) o[c] = sb[mtx * 24 + c];
        #pragma unroll
        for (int ci = 0; ci < 24; ci++) {
            float hv = hx[ci];
            #pragma unroll
            for (int c = 0; c < 24; c++)
                o[c] += hv * sW[mtx * 576 + ci * 24 + c];
        }
        if (mtx == 0 || mtx == 3) {
            float* dst = (mtx == 0) ? (q + (size_t)node * DCH)
                                    : (skip + (size_t)node * DCH);
            float4* op = (float4*)dst;
            #pragma unroll
            for (int t = 0; t < 6; t++) {
                float4 f;
                f.x = o[4*t]; f.y = o[4*t+1]; f.z = o[4*t+2]; f.w = o[4*t+3];
                op[t] = f;
            }
        } else {
            __half tmp[24];
            #pragma unroll
            for (int c = 0; c < 24; c++) tmp[c] = __float2half_rn(o[c]);
            float4* op = (float4*)(kv + (size_t)node * KVROW + (mtx == 1 ? 0 : 24));
            const float4* tp = (const float4*)tmp;
            #pragma unroll
            for (int t = 0; t < 3; t++) op[t] = tp[t];
        }
    }
}

// ---------------- CSR build: slack-bin bucket sort, 512-node bins ----------------
__global__ void cursor_init_kernel(int* __restrict__ cursor)
{
    int t = blockIdx.x * 256 + threadIdx.x;
    if (t < NBINS) cursor[t] = t * CAP;
}

__global__ __launch_bounds__(512) void partition_kernel(
    const int* __restrict__ esrc, const int* __restrict__ edst,
    int* __restrict__ cursor, unsigned int* __restrict__ bucket)
{
    __shared__ int hist[NBINS_P];
    __shared__ int base[NBINS_P];
    for (int t = threadIdx.x; t < NBINS_P; t += 512) hist[t] = 0;
    __syncthreads();
    int e0 = blockIdx.x * EPB;
    int e1 = min(e0 + EPB, N_EDGES);
    for (int e = e0 + threadIdx.x; e < e1; e += 512)
        atomicAdd(&hist[edst[e] >> BINSHIFT], 1);
    __syncthreads();
    for (int t = threadIdx.x; t < NBINS; t += 512) {
        int hcount = hist[t];
        base[t] = hcount ? atomicAdd(&cursor[t], hcount) : 0;
    }
    __syncthreads();
    for (int t = threadIdx.x; t < NBINS_P; t += 512) hist[t] = 0;
    __syncthreads();
    for (int e = e0 + threadIdx.x; e < e1; e += 512) {
        int d = edst[e];
        int b = d >> BINSHIFT;
        int lc = atomicAdd(&hist[b], 1);
        int pos = base[b] + lc;
        if (pos < (b + 1) * CAP)  // overflow guard (never fires for uniform input)
            bucket[pos] = ((unsigned)(d & (BINSZ - 1)) << 17) | (unsigned)esrc[e];
    }
}

__global__ __launch_bounds__(256) void bin_scan_kernel(
    const int* __restrict__ cursor,
    int* __restrict__ bin_base, int* __restrict__ row_start)
{
    __shared__ int sd[256];
    int t = threadIdx.x;
    int v = 0;
    if (t < NBINS) v = min(cursor[t] - t * CAP, CAP);
    sd[t] = v;
    __syncthreads();
    for (int off = 1; off < 256; off <<= 1) {
        int u = (t >= off) ? sd[t - off] : 0;
        __syncthreads();
        sd[t] += u;
        __syncthreads();
    }
    if (t < NBINS) bin_base[t] = sd[t] - v;  // exclusive prefix
    if (t == 0) { bin_base[NBINS] = N_EDGES; row_start[N_NODES] = N_EDGES; }
}

__global__ __launch_bounds__(512) void bin_scatter_kernel(
    const unsigned int* __restrict__ bucket, const int* __restrict__ cursor,
    const int* __restrict__ bin_base,
    int* __restrict__ row_start, int* __restrict__ csr_src)
{
    int b = blockIdx.x;
    int node0 = b << BINSHIFT;
    int nn = min(BINSZ, N_NODES - node0);
    int ebeg = b * CAP;
    int cnt  = min(cursor[b] - b * CAP, CAP);
    int obase = bin_base[b];
    __shared__ int c0[BINSZ], s[BINSZ], cur[BINSZ];
    int tid = threadIdx.x;
    c0[tid] = 0;
    __syncthreads();
    for (int i = tid; i < cnt; i += 512)
        atomicAdd(&c0[bucket[ebeg + i] >> 17], 1);
    __syncthreads();
    s[tid] = c0[tid];
    __syncthreads();
    for (int off = 1; off < 512; off <<= 1) {
        int u = (tid >= off) ? s[tid - off] : 0;
        __syncthreads();
        s[tid] += u;
        __syncthreads();
    }
    if (tid < nn) {
        int ex = obase + s[tid] - c0[tid];
        row_start[node0 + tid] = ex;
        cur[tid] = ex;
    }
    __syncthreads();
    for (int i = tid; i < cnt; i += 512) {
        unsigned p = bucket[ebeg + i];
        int j = p >> 17;
        int pos = atomicAdd(&cur[j], 1);
        csr_src[pos] = (int)(p & 0x1FFFF);
    }
}

// ---------------- fused attention ----------------
// MODE 0: tail-fuse next layer's linear (q/kv/skip). Weight staging + barrier at
//         kernel START (cheap, uniform); after that every 8-lane group runs
//         gather -> merge -> tail GEMV -> write fully independently (no mid-kernel
//         barrier -> no slowest-node-in-block coupling; r11 lesson).
// MODE 1: last layer; epilogue accumulates graph mean-pool.
// Grid is exactly N_NODES/32 blocks (100000 % 32 == 0).
#define LPN 8
template<int MODE>
__global__ __launch_bounds__(256) void attn_fused(
    const float* __restrict__ q, const __half* __restrict__ kv,
    const float* __restrict__ skip,
    const int* __restrict__ row_start, const int* __restrict__ csr_src,
    const float* __restrict__ Wqn, const float* __restrict__ bqn,
    const float* __restrict__ Wkn, const float* __restrict__ bkn,
    const float* __restrict__ Wvn, const float* __restrict__ bvn,
    const float* __restrict__ Wsn, const float* __restrict__ bsn,
    float* __restrict__ qn, __half* __restrict__ kvn, float* __restrict__ skipn,
    const int* __restrict__ batch, float* __restrict__ poolc)
{
    __shared__ float sW[4 * 576];
    __shared__ float sb[4 * 24];
    __shared__ float spool[8][25];

    int tid = threadIdx.x;
    int node0 = blockIdx.x * 32;

    if (MODE == 0) {
        // stage next-layer weights, then ONE barrier at start (uniform, ~9 floats/thread)
        for (int t = tid; t < 576; t += 256) {
            sW[t]        = Wqn[t];
            sW[576 + t]  = Wkn[t];
            sW[1152 + t] = Wvn[t];
            sW[1728 + t] = Wsn[t];
        }
        if (tid < 24) {
            sb[tid]      = bqn[tid];
            sb[24 + tid] = bkn[tid];
            sb[48 + tid] = bvn[tid];
            sb[72 + tid] = bsn[tid];
        }
        __syncthreads();
    } else {
        for (int t = tid; t < 8 * 25; t += 256) ((float*)spool)[t] = 0.f;
        __syncthreads();
    }

    int i   = node0 + (tid >> 3);
    int sub = tid & (LPN - 1);

    float qr[24];
    const float4* qp = (const float4*)(q + (size_t)i * DCH);
    #pragma unroll
    for (int t = 0; t < 6; t++) {
        float4 f = qp[t];
        qr[4*t] = f.x; qr[4*t+1] = f.y; qr[4*t+2] = f.z; qr[4*t+3] = f.w;
    }

    float m = -INFINITY, s = 0.f;
    float acc[24];
    #pragma unroll
    for (int c = 0; c < 24; c++) acc[c] = 0.f;

    int beg = row_start[i];
    int end = row_start[i + 1];
    const float scale = 0.2041241452319315f;  // 1/sqrt(24)

    int src_next = (beg + sub < end) ? csr_src[beg + sub] : 0;
    for (int e = beg + sub; e < end; e += LPN) {
        int src = src_next;
        src_next = (e + LPN < end) ? csr_src[e + LPN] : 0;

        const float4* kvp = (const float4*)(kv + (size_t)src * KVROW);
        float4 kr[3], vr[3];
        #pragma unroll
        for (int t = 0; t < 3; t++) kr[t] = kvp[t];
        #pragma unroll
        for (int t = 0; t < 3; t++) vr[t] = kvp[3 + t];

        const __half2* kh = (const __half2*)kr;
        float dot = 0.f;
        #pragma unroll
        for (int j = 0; j < 12; j++) {
            float2 f = __half22float2(kh[j]);
            dot += qr[2*j] * f.x + qr[2*j+1] * f.y;
        }
        dot *= scale;

        float mn   = fmaxf(m, dot);
        float wold = __expf(m - mn);   // first iter: exp(-inf)=0
        float w    = __expf(dot - mn);
        s = s * wold + w;
        const __half2* vh = (const __half2*)vr;
        #pragma unroll
        for (int j = 0; j < 12; j++) {
            float2 f = __half22float2(vh[j]);
            acc[2*j]   = acc[2*j]   * wold + w * f.x;
            acc[2*j+1] = acc[2*j+1] * wold + w * f.y;
        }
        m = mn;
    }

    // butterfly merge: ALL lanes end with the merged (m, s, acc)
    #pragma unroll
    for (int off = 1; off < LPN; off <<= 1) {
        float m2 = __shfl_xor(m, off);
        float s2 = __shfl_xor(s, off);
        float mn = fmaxf(m, m2);
        float w1 = (m  == mn) ? 1.f : __expf(m  - mn);  // avoids (-inf)-(-inf)=NaN
        float w2 = (m2 == mn) ? 1.f : __expf(m2 - mn);
        s = s * w1 + s2 * w2;
        #pragma unroll
        for (int c = 0; c < 24; c++) {
            float a2 = __shfl_xor(acc[c], off);
            acc[c] = acc[c] * w1 + a2 * w2;
        }
        m = mn;
    }

    if (MODE == 0) {
        // no barrier here: weights were ready before the gather loop began
        float inv = 1.f / (s + 1e-16f);
        float hrow[24];
        const float4* sp = (const float4*)(skip + (size_t)i * DCH);
        #pragma unroll
        for (int t = 0; t < 6; t++) {
            float4 f = sp[t];
            hrow[4*t]   = fmaxf(f.x + acc[4*t]   * inv, 0.f);
            hrow[4*t+1] = fmaxf(f.y + acc[4*t+1] * inv, 0.f);
            hrow[4*t+2] = fmaxf(f.z + acc[4*t+2] * inv, 0.f);
            hrow[4*t+3] = fmaxf(f.w + acc[4*t+3] * inv, 0.f);
        }
        int c0 = 3 * sub;
        float oq0 = sb[c0],      oq1 = sb[c0+1],      oq2 = sb[c0+2];
        float ok0 = sb[24+c0],   ok1 = sb[24+c0+1],   ok2 = sb[24+c0+2];
        float ov0 = sb[48+c0],   ov1 = sb[48+c0+1],   ov2 = sb[48+c0+2];
        float os0 = sb[72+c0],   os1 = sb[72+c0+1],   os2 = sb[72+c0+2];
        #pragma unroll
        for (int ci = 0; ci < 24; ci++) {
            float hv = hrow[ci];
            const float* w = &sW[ci * 24 + c0];
            oq0 += hv * w[0];    oq1 += hv * w[1];    oq2 += hv * w[2];
            ok0 += hv * w[576];  ok1 += hv * w[577];  ok2 += hv * w[578];
            ov0 += hv * w[1152]; ov1 += hv * w[1153]; ov2 += hv * w[1154];
            os0 += hv * w[1728]; os1 += hv * w[1729]; os2 += hv * w[1730];
        }
        float* qo = qn + (size_t)i * DCH + c0;
        qo[0] = oq0; qo[1] = oq1; qo[2] = oq2;
        float* so = skipn + (size_t)i * DCH + c0;
        so[0] = os0; so[1] = os1; so[2] = os2;
        __half* kp = kvn + (size_t)i * KVROW + c0;
        kp[0] = __float2half_rn(ok0); kp[1] = __float2half_rn(ok1); kp[2] = __float2half_rn(ok2);
        __half* vp = kvn + (size_t)i * KVROW + 24 + c0;
        vp[0] = __float2half_rn(ov0); vp[1] = __float2half_rn(ov1); vp[2] = __float2half_rn(ov2);
    } else {
        // pool epilogue: lane sub handles channels 3sub..3sub+2
        float inv = 1.f / (s + 1e-16f);
        const float* sp = skip + (size_t)i * DCH + 3 * sub;
        float o0 = fmaxf(sp[0] + acc[3*sub]     * inv, 0.f);
        float o1 = fmaxf(sp[1] + acc[3*sub + 1] * inv, 0.f);
        float o2 = fmaxf(sp[2] + acc[3*sub + 2] * inv, 0.f);
        int g  = batch[i];
        int g0 = batch[node0];
        int rel = g - g0;
        if (rel < 8) {
            atomicAdd(&spool[rel][3*sub],     o0);
            atomicAdd(&spool[rel][3*sub + 1], o1);
            atomicAdd(&spool[rel][3*sub + 2], o2);
            if (sub == 0) atomicAdd(&spool[rel][24], 1.f);
        } else {
            atomicAdd(&poolc[g * 25 + 3*sub],     o0);
            atomicAdd(&poolc[g * 25 + 3*sub + 1], o1);
            atomicAdd(&poolc[g * 25 + 3*sub + 2], o2);
            if (sub == 0) atomicAdd(&poolc[g * 25 + 24], 1.f);
        }
        __syncthreads();
        for (int t = tid; t < 8 * 25; t += 256) {
            int slot = t / 25, c = t % 25;
            float val = spool[slot][c];
            if (val != 0.f)
                atomicAdd(&poolc[(g0 + slot) * 25 + c], val);
        }
    }
}

// ---------------- final MLP: one block per graph ----------------
__global__ __launch_bounds__(128) void mlp_kernel(
    const float* __restrict__ poolc,
    const float* __restrict__ gf,
    const float* __restrict__ gfW1, const float* __restrict__ gfb1,
    const float* __restrict__ gfW2, const float* __restrict__ gfb2,
    const float* __restrict__ W1, const float* __restrict__ b1,
    const float* __restrict__ W2, const float* __restrict__ b2,
    const float* __restrict__ W3, const float* __restrict__ b3,
    float* __restrict__ out)
{
    int g = blockIdx.x;
    int t = threadIdx.x;
    __shared__ float z[36];
    __shared__ float g1[12];
    __shared__ float h1[128];
    __shared__ float h2[128];
    __shared__ float wsum[2];

    if (t < 12) {
        float a = gfb1[t];
        #pragma unroll
        for (int j = 0; j < 6; j++) a += gf[g * 6 + j] * gfW1[j * 12 + t];
        g1[t] = fmaxf(a, 0.f);
    }
    if (t < 24) {
        float c = fmaxf(poolc[g * 25 + 24], 1.f);
        z[t] = poolc[g * 25 + t] / c;
    }
    __syncthreads();
    if (t < 12) {
        float a = gfb2[t];
        #pragma unroll
        for (int j = 0; j < 12; j++) a += g1[j] * gfW2[j * 12 + t];
        z[24 + t] = fmaxf(a, 0.f);
    }
    __syncthreads();
    {
        float a = b1[t];
        #pragma unroll
        for (int j = 0; j < 36; j++) a += z[j] * W1[j * 128 + t];
        h1[t] = fmaxf(a, 0.f);
    }
    __syncthreads();
    {
        float a = b2[t];
        for (int j = 0; j < 128; j++) a += h1[j] * W2[j * 128 + t];
        h2[t] = fmaxf(a, 0.f);
    }
    __syncthreads();
    float p = h2[t] * W3[t];
    for (int off = 32; off; off >>= 1) p += __shfl_down(p, off);
    if ((t & 63) == 0) wsum[t >> 6] = p;
    __syncthreads();
    if (t == 0) out[g] = wsum[0] + wsum[1] + b3[0];
}

// ---------------- launch ----------------
extern "C" void kernel_launch(void* const* d_in, const int* in_sizes, int n_in,
                              void* d_out, int out_size, void* d_ws, size_t ws_size,
                              hipStream_t stream)
{
    const float* x     = (const float*)d_in[0];
    const int*   ei    = (const int*)d_in[1];
    const int*   batch = (const int*)d_in[2];
    const float* gf    = (const float*)d_in[3];
    const float* Wq    = (const float*)d_in[4];
    const float* bq    = (const float*)d_in[5];
    const float* Wk    = (const float*)d_in[6];
    const float* bk    = (const float*)d_in[7];
    const float* Wv    = (const float*)d_in[8];
    const float* bv    = (const float*)d_in[9];
    const float* Ws    = (const float*)d_in[10];
    const float* bs    = (const float*)d_in[11];
    const float* gfW1  = (const float*)d_in[12];
    const float* gfb1  = (const float*)d_in[13];
    const float* gfW2  = (const float*)d_in[14];
    const float* gfb2  = (const float*)d_in[15];
    const float* W1    = (const float*)d_in[16];
    const float* b1    = (const float*)d_in[17];
    const float* W2    = (const float*)d_in[18];
    const float* b2    = (const float*)d_in[19];
    const float* W3    = (const float*)d_in[20];
    const float* b3    = (const float*)d_in[21];
    float* out = (float*)d_out;

    const int* esrc = ei;
    const int* edst = ei + N_EDGES;

    // workspace layout
    char* ws = (char*)d_ws;
    size_t off = 0;
    auto alloc = [&](size_t bytes) -> void* {
        void* p = ws + off;
        off = (off + bytes + 255) & ~(size_t)255;
        return p;
    };
    float*  qA   = (float*)alloc((size_t)N_NODES * DCH * 4);
    __half* kvA  = (__half*)alloc((size_t)N_NODES * KVROW * 2);
    float*  skA  = (float*)alloc((size_t)N_NODES * DCH * 4);
    float*  qB   = (float*)alloc((size_t)N_NODES * DCH * 4);
    float*  skB  = (float*)alloc((size_t)N_NODES * DCH * 4);
    int* row_start   = (int*)alloc(((size_t)N_NODES + 1) * 4);
    int* csr_src     = (int*)alloc((size_t)N_EDGES * 4);
    // bucket (13.65 MB) is dead after bin_scatter; kvB (12.8 MB) aliases it.
    unsigned int* bucket = (unsigned int*)alloc((size_t)NBINS * CAP * 4);
    __half* kvB  = (__half*)bucket;
    int* bin_base    = (int*)alloc((size_t)(NBINS + 1) * 4);
    int* bin_cursor  = (int*)alloc((size_t)NBINS_P * 4);
    float* poolc     = (float*)alloc((size_t)N_GRAPHS * 25 * 4);

    const int NB_NODE = (N_NODES + 255) / 256;
    const int NB_ATTN = N_NODES / 32;  // 3125, exact (100000 % 32 == 0)

    // ---- CSR build: slack-bin bucket sort (512-node bins) ----
    cursor_init_kernel<<<1, 256, 0, stream>>>(bin_cursor);
    partition_kernel<<<NB_PART, 512, 0, stream>>>(esrc, edst, bin_cursor, bucket);
    bin_scan_kernel<<<1, 256, 0, stream>>>(bin_cursor, bin_base, row_start);
    bin_scatter_kernel<<<NBINS, 512, 0, stream>>>(bucket, bin_cursor, bin_base, row_start, csr_src);

    hipMemsetAsync(poolc, 0, (size_t)N_GRAPHS * 25 * 4, stream);

    // ---- layer 0 linear from x ----
    lin_kernel<<<NB_NODE, 256, 0, stream>>>(
        x, Wq, bq, Wk, bk, Wv, bv, Ws, bs, qA, kvA, skA);

    // ---- layers 0..2: attn with tail-fused next-layer linear (ping-pong A/B) ----
    attn_fused<0><<<NB_ATTN, 256, 0, stream>>>(
        qA, kvA, skA, row_start, csr_src,
        Wq + 1*576, bq + 1*24, Wk + 1*576, bk + 1*24,
        Wv + 1*576, bv + 1*24, Ws + 1*576, bs + 1*24,
        qB, kvB, skB, nullptr, nullptr);
    attn_fused<0><<<NB_ATTN, 256, 0, stream>>>(
        qB, kvB, skB, row_start, csr_src,
        Wq + 2*576, bq + 2*24, Wk + 2*576, bk + 2*24,
        Wv + 2*576, bv + 2*24, Ws + 2*576, bs + 2*24,
        qA, kvA, skA, nullptr, nullptr);
    attn_fused<0><<<NB_ATTN, 256, 0, stream>>>(
        qA, kvA, skA, row_start, csr_src,
        Wq + 3*576, bq + 3*24, Wk + 3*576, bk + 3*24,
        Wv + 3*576, bv + 3*24, Ws + 3*576, bs + 3*24,
        qB, kvB, skB, nullptr, nullptr);

    // ---- layer 3: attn with fused mean-pool ----
    attn_fused<1><<<NB_ATTN, 256, 0, stream>>>(
        qB, kvB, skB, row_start, csr_src,
        nullptr, nullptr, nullptr, nullptr, nullptr, nullptr, nullptr, nullptr,
        nullptr, nullptr, nullptr, batch, poolc);

    // ---- MLP ----
    mlp_kernel<<<N_GRAPHS, 128, 0, stream>>>(
        poolc, gf, gfW1, gfb1, gfW2, gfb2, W1, b1, W2, b2, W3, b3, out);
}